// Round 7
// baseline (233.781 us; speedup 1.0000x reference)
//
#include <hip/hip_runtime.h>

#define NUM_SEG 32
#define MUL 128
#define D 3
#define NUM_PATHS 64
#define ROW (NUM_SEG * MUL * D)   // 12288 floats per batch row
#define SEGF (MUL * D)            // 384 floats per full segment row

typedef float v2f __attribute__((ext_vector_type(2)));
typedef float v4f __attribute__((ext_vector_type(4)));

// ---------------------------------------------------------------------------
// Single kernel, one block per batch row.
//  - 48 KB x0 row staged with 12 fully-contiguous global_load_lds16/thread
//  - schedule + m built by wave 0 UNDER the DMA (raw lgkm-only barrier first;
//    full vmcnt drain only at the second barrier)
//  - wave w owns seg-slots; count-sorted snake ranks balance the 4 waves;
//    entry stream is wave-uniform -> no divergence, broadcast m reads
//  - XCD-chunked bijective swizzle: each XCD streams a contiguous b-range
// ---------------------------------------------------------------------------
__global__ __launch_bounds__(256) void ftp_kernel(
    const float* __restrict__ x0, const float* __restrict__ x1,
    const float* __restrict__ coeff, const int* __restrict__ idx0,
    const int* __restrict__ idx1, const int* __restrict__ idx2,
    float* __restrict__ out, int swz)
{
    const int bid = blockIdx.x;
    const int nb  = gridDim.x;
    const int b   = swz ? ((bid & 7) * (nb >> 3) + (bid >> 3)) : bid;
    const int tid = threadIdx.x;

    __shared__ __align__(16) float s_x0[ROW];            // 49152 B, row layout
    __shared__ __align__(16) float s_m[NUM_PATHS][9];    //  2304 B
    __shared__ int s_cnt[NUM_SEG];
    __shared__ int s_off[NUM_SEG];
    __shared__ int s_perm[NUM_SEG];
    __shared__ unsigned int s_sched[NUM_SEG];
    __shared__ unsigned short s_ent[NUM_PATHS];

    // ---- issue full-row contiguous async stage FIRST: 12 x gl_lds16 ----
    const v4f* __restrict__ src = (const v4f*)(x0 + (size_t)b * ROW);
    #pragma unroll
    for (int j = 0; j < 12; ++j) {
        const int F = j * 256 + tid;          // linear [0,3072): global==LDS order
        __builtin_amdgcn_global_load_lds(
            (const __attribute__((address_space(1))) void*)(src + F),
            (__attribute__((address_space(3))) void*)((v4f*)s_x0 + F),
            16, 0, 0);
    }

    if (tid < NUM_SEG) s_cnt[tid] = 0;
    // LDS-only barrier: do NOT drain the staging vmcnt here
    asm volatile("s_waitcnt lgkmcnt(0)" ::: "memory");
    __builtin_amdgcn_s_barrier();

    // ---- wave 0: schedule + m, overlapped with the DMA ----
    if (tid < NUM_PATHS) {
        const int p  = tid;
        const int s2 = idx2[p];
        const int s0 = idx0[p];
        const float* xr = x1 + (size_t)b * (NUM_SEG * D) + idx1[p] * D;
        const float j0 = xr[0], j1 = xr[1], j2 = xr[2];
        const float* cf = coeff + p * 27;     // coeff[p][i][j][k]
        float mv[9];
        #pragma unroll
        for (int i = 0; i < D; ++i)
            #pragma unroll
            for (int k = 0; k < D; ++k)
                mv[i * 3 + k] = j0 * cf[i * 9 + k]
                              + j1 * cf[i * 9 + 3 + k]
                              + j2 * cf[i * 9 + 6 + k];

        const int pos = atomicAdd(&s_cnt[s2], 1);   // whole wave: one ds_atomic
        if (tid == 0) {                             // same wave, DS in-order
            int off = 0;
            #pragma unroll
            for (int s = 0; s < NUM_SEG; ++s) { s_off[s] = off; off += s_cnt[s]; }
            int perm[NUM_SEG];
            for (int s = 0; s < NUM_SEG; ++s) perm[s] = s;
            for (int i = 1; i < NUM_SEG; ++i) {     // insertion sort, cnt desc
                int v = perm[i], cv = s_cnt[v], j = i - 1;
                while (j >= 0 && s_cnt[perm[j]] < cv) { perm[j + 1] = perm[j]; --j; }
                perm[j + 1] = v;
            }
            for (int s = 0; s < NUM_SEG; ++s) s_perm[s] = perm[s];
        }
        s_ent[s_off[s2] + pos] = (unsigned short)(s0 | (p << 8));
        if (tid < NUM_SEG) {
            const int sg = s_perm[tid];
            s_sched[tid] = (unsigned)s_cnt[sg] | ((unsigned)s_off[sg] << 8)
                         | ((unsigned)sg << 16);
        }
        #pragma unroll
        for (int i = 0; i < 9; ++i) s_m[p][i] = mv[i];
    }

    // ---- full drain: staging landed + wave-0 LDS writes visible ----
    asm volatile("s_waitcnt vmcnt(0) lgkmcnt(0)" ::: "memory");
    __builtin_amdgcn_s_barrier();

    // ---- compute: wave w = seg-slot (uniform), q = u-pair over full row ----
    const int q = tid & 63;            // local u = 2q, 2q+1 (u in [0,128))
    const int w = tid >> 6;            // wave id = slot
    float* __restrict__ ob = out + (size_t)b * ROW + q * 6;

    #pragma unroll
    for (int si = 0; si < 8; ++si) {
        // snake over count-sorted ranks: waves get {0,7,8,15,...} etc -> balanced
        const int rank = si * 4 + ((si & 1) ? (3 - w) : w);
        const unsigned sc = s_sched[rank];
        const int n   = sc & 255;
        const int off = (sc >> 8) & 255;
        const int s   = sc >> 16;
        float a00 = 0, a01 = 0, a02 = 0, a10 = 0, a11 = 0, a12 = 0;
        for (int t = 0; t < n; ++t) {
            const int e = s_ent[off + t];            // wave-uniform entry
            const float* xs = s_x0 + (e & 255) * SEGF + q * 6;
            const float u00 = xs[0], u01 = xs[1], u02 = xs[2];
            const float u10 = xs[3], u11 = xs[4], u12 = xs[5];
            const float* mm = s_m[e >> 8];           // wave-uniform broadcast
            a00 += u00 * mm[0] + u01 * mm[3] + u02 * mm[6];
            a01 += u00 * mm[1] + u01 * mm[4] + u02 * mm[7];
            a02 += u00 * mm[2] + u01 * mm[5] + u02 * mm[8];
            a10 += u10 * mm[0] + u11 * mm[3] + u12 * mm[6];
            a11 += u10 * mm[1] + u11 * mm[4] + u12 * mm[7];
            a12 += u10 * mm[2] + u11 * mm[5] + u12 * mm[8];
        }
        float* o = ob + s * SEGF;      // wave covers the seg's full 1536B span
        v2f O0 = {a00, a01}, O1 = {a02, a10}, O2 = {a11, a12};
        *(v2f*)(o + 0) = O0;
        *(v2f*)(o + 2) = O1;
        *(v2f*)(o + 4) = O2;
    }
}

extern "C" void kernel_launch(void* const* d_in, const int* in_sizes, int n_in,
                              void* d_out, int out_size, void* d_ws, size_t ws_size,
                              hipStream_t stream) {
    const float* x0    = (const float*)d_in[0];
    const float* x1    = (const float*)d_in[1];
    const float* coeff = (const float*)d_in[2];
    const int*   idx0  = (const int*)d_in[3];
    const int*   idx1  = (const int*)d_in[4];
    const int*   idx2  = (const int*)d_in[5];
    float* out = (float*)d_out;

    const int B = in_sizes[0] / ROW;
    const int swz = (B % 8 == 0) ? 1 : 0;
    ftp_kernel<<<B, 256, 0, stream>>>(x0, x1, coeff, idx0, idx1, idx2, out, swz);
}